// Round 4
// baseline (245.835 us; speedup 1.0000x reference)
//
#include <hip/hip_runtime.h>
#include <hip/hip_bf16.h>
#include <math.h>

// VSN fused: B=32,T=512,V=16,D=128. bf16 MFMA, barrier-minimal structure.
#define NVAR 16
#define ND 128
#define NVD 2048
#define NR 16          // rows per block
#define NTH 512        // 8 waves
#define NROWS 16384
#define NBLK (NROWS/NR)

typedef short s16x8 __attribute__((ext_vector_type(8)));
typedef short s16x4 __attribute__((ext_vector_type(4)));
typedef float f32x4 __attribute__((ext_vector_type(4)));
typedef unsigned short u16;

#define MFMA(a,b,c) __builtin_amdgcn_mfma_f32_16x16x32_bf16((a),(b),(c),0,0,0)

// ws layout (u16 elements)
#define OFF_W2  0
#define OFF_WG  262144
#define OFF_SW1 524288
#define OFF_SWS 786432
#define OFF_SW2 819200
#define OFF_SWG 821248
#define WS_ELEMS 823296

__device__ __forceinline__ unsigned f2bf(float f){
    union { float f; unsigned u; } c; c.f = f;
    unsigned u = c.u;
    u += 0x7fffu + ((u >> 16) & 1u);   // RNE
    return u >> 16;
}
__device__ __forceinline__ float bf2f(unsigned bits){
    union { unsigned u; float f; } c; c.u = bits << 16;
    return c.f;
}
__device__ __forceinline__ float eluf(float x){ return x > 0.f ? x : expm1f(x); }
__device__ __forceinline__ float sigm(float x){ return 1.f/(1.f+expf(-x)); }

// XOR-swizzled LDS offsets (u16 units); 16B units XOR'd by row&7.
__device__ __forceinline__ int offBig(int r, int c){
    return r*2048 + ((((c>>3) ^ (r&7))<<3) | (c&7));
}
__device__ __forceinline__ int offHs(int r, int c){
    return r*128 + ((((c>>3) ^ (r&7))<<3) | (c&7));
}

__global__ void prep_kernel(const float* __restrict__ W2, const float* __restrict__ Wg,
                            const float* __restrict__ sW1, const float* __restrict__ sWs,
                            const float* __restrict__ sW2, const float* __restrict__ sWg,
                            u16* __restrict__ ws){
    int i = blockIdx.x*256 + threadIdx.x;
    if (i >= WS_ELEMS) return;
    float v;
    if      (i < OFF_WG)  v = W2[i];
    else if (i < OFF_SW1) v = Wg[i-OFF_WG];
    else if (i < OFF_SWS) v = sW1[i-OFF_SW1];
    else if (i < OFF_SW2) v = sWs[i-OFF_SWS];
    else if (i < OFF_SWG) v = sW2[i-OFF_SW2];
    else                  v = sWg[i-OFF_SWG];
    ws[i] = (u16)f2bf(v);
}

__global__ __launch_bounds__(NTH, 4)
void vsn_main(const float* __restrict__ x,
              const float* __restrict__ W1, const float* __restrict__ b1,
              const float* __restrict__ b2, const float* __restrict__ bg,
              const float* __restrict__ Wsk, const float* __restrict__ bsk,
              const float* __restrict__ gamma, const float* __restrict__ beta,
              const float* __restrict__ sb1, const float* __restrict__ sb2,
              const float* __restrict__ sbg, const float* __restrict__ sbs,
              const float* __restrict__ sgamma, const float* __restrict__ sbeta,
              const u16* __restrict__ ws,
              float* __restrict__ out_proc, float* __restrict__ out_w)
{
    __shared__ u16   big[NR*2048];   // h (transient) then stacked bf16, swizzled
    __shared__ u16   hsb[NR*128];    // hs bf16, swizzled
    __shared__ float pp[8*256];      // cross-wave MFMA partials
    __shared__ float wgtbuf[256];    // softmax weights
    __shared__ float sksbuf[256];    // sks
    __shared__ float sx[NR*NVAR];

    const int t   = threadIdx.x;
    const int w   = t >> 6;
    const int l   = t & 63;
    const int hr  = l >> 4;        // 0..3
    const int c16 = l & 15;
    const int row0 = blockIdx.x * NR;
    const int orow = w*16 + c16;

    if (t < NR*NVAR) sx[t] = x[row0*NVAR + t];
    __syncthreads();

    // ---------------- (1) h = elu(x*W1+b1) for ALL vars ----------------
    #pragma unroll
    for (int i = 0; i < 8; ++i){
        int flat = (i*NTH + t)*8;
        int r = flat >> 11;
        int col = flat & 2047;
        float xv = sx[r*NVAR + (col>>7)];
        const float4* w1p = reinterpret_cast<const float4*>(&W1[col]);
        const float4* b1p = reinterpret_cast<const float4*>(&b1[col]);
        float4 wa = w1p[0], wb = w1p[1], ba = b1p[0], bb = b1p[1];
        s16x8 o;
        o[0] = (short)f2bf(eluf(xv*wa.x+ba.x));
        o[1] = (short)f2bf(eluf(xv*wa.y+ba.y));
        o[2] = (short)f2bf(eluf(xv*wa.z+ba.z));
        o[3] = (short)f2bf(eluf(xv*wa.w+ba.w));
        o[4] = (short)f2bf(eluf(xv*wb.x+bb.x));
        o[5] = (short)f2bf(eluf(xv*wb.y+bb.y));
        o[6] = (short)f2bf(eluf(xv*wb.z+bb.z));
        o[7] = (short)f2bf(eluf(xv*wb.w+bb.w));
        *reinterpret_cast<s16x8*>(&big[offBig(r, col)]) = o;
    }
    __syncthreads();   // h ready for all vars

    // ---------------- (2) per-var GRNs: wave w owns vars w and w+8 -------
    // Swapped MFMA: D = W_frag . h_frag  ->  lane holds n-row c16, dims hr*4+j
    const u16* W2b = ws + OFF_W2;
    const u16* Wgb = ws + OFF_WG;
    #pragma unroll 1
    for (int vi = 0; vi < 2; ++vi){
        const int v = w + vi*8;
        s16x8 A[4];
        #pragma unroll
        for (int ks = 0; ks < 4; ++ks)
            A[ks] = *reinterpret_cast<const s16x8*>(&big[offBig(c16, v*ND + ks*32 + hr*8)]);
        const u16* B2base = W2b + v*ND*ND + hr*8;
        const u16* Bgbase = Wgb + v*ND*ND + hr*8;
        const float xnv = sx[c16*NVAR + v];
        float y[8][4];
        #pragma unroll
        for (int ct = 0; ct < 8; ++ct){
            const s16x8* B2p = reinterpret_cast<const s16x8*>(B2base + (ct*16+c16)*ND);
            const s16x8* Bgp = reinterpret_cast<const s16x8*>(Bgbase + (ct*16+c16)*ND);
            f32x4 a2 = {0.f,0.f,0.f,0.f}, ag = {0.f,0.f,0.f,0.f};
            #pragma unroll
            for (int ks = 0; ks < 4; ++ks) a2 = MFMA(B2p[ks*4], A[ks], a2);
            #pragma unroll
            for (int ks = 0; ks < 4; ++ks) ag = MFMA(Bgp[ks*4], A[ks], ag);
            const int dbase = v*ND + ct*16 + hr*4;
            float4 b2v = *reinterpret_cast<const float4*>(&b2[dbase]);
            float4 bgv = *reinterpret_cast<const float4*>(&bg[dbase]);
            float4 wsv = *reinterpret_cast<const float4*>(&Wsk[dbase]);
            float4 bsv = *reinterpret_cast<const float4*>(&bsk[dbase]);
            #pragma unroll
            for (int j = 0; j < 4; ++j){
                float h2 = a2[j] + reinterpret_cast<const float*>(&b2v)[j];
                float g  = sigm(ag[j] + reinterpret_cast<const float*>(&bgv)[j]);
                float sk = xnv*reinterpret_cast<const float*>(&wsv)[j]
                           + reinterpret_cast<const float*>(&bsv)[j];
                y[ct][j] = g*h2 + (1.f-g)*sk;
            }
        }
        // wave-local LN over the 128 dims of n-row c16
        float s = 0.f, q = 0.f;
        #pragma unroll
        for (int ct = 0; ct < 8; ++ct)
            #pragma unroll
            for (int j = 0; j < 4; ++j){ float yy = y[ct][j]; s += yy; q += yy*yy; }
        s += __shfl_xor(s, 16); s += __shfl_xor(s, 32);
        q += __shfl_xor(q, 16); q += __shfl_xor(q, 32);
        float mean = s*(1.f/ND);
        float inv  = rsqrtf(q*(1.f/ND) - mean*mean + 1e-5f);
        #pragma unroll
        for (int ct = 0; ct < 8; ++ct){
            const int dbase = v*ND + ct*16 + hr*4;
            float4 gm = *reinterpret_cast<const float4*>(&gamma[dbase]);
            float4 bt = *reinterpret_cast<const float4*>(&beta[dbase]);
            s16x4 o;
            #pragma unroll
            for (int j = 0; j < 4; ++j){
                float z = (y[ct][j]-mean)*inv*reinterpret_cast<const float*>(&gm)[j]
                          + reinterpret_cast<const float*>(&bt)[j];
                o[j] = (short)f2bf(z);
            }
            *reinterpret_cast<s16x4*>(&big[offBig(c16, dbase - v*ND + v*ND)]) = o; // big[offBig(c16,dbase)]
        }
    }
    __syncthreads();   // stacked fully ready

    // ---------------- softmax GRN ----------------
    // (2a) hs = elu(flat . sW1^T + sb1): wave w -> cols w*16..+15, K=2048
    const u16* sW1b = ws + OFF_SW1;
    {
        f32x4 acc0 = {0,0,0,0}, acc1 = {0,0,0,0};
        const s16x8* Bp = reinterpret_cast<const s16x8*>(sW1b + orow*NVD + hr*8);
        #pragma unroll 8
        for (int ks = 0; ks < 64; ks += 2){
            s16x8 A0 = *reinterpret_cast<const s16x8*>(&big[offBig(c16, ks*32 + hr*8)]);
            s16x8 A1 = *reinterpret_cast<const s16x8*>(&big[offBig(c16, (ks+1)*32 + hr*8)]);
            acc0 = MFMA(A0, Bp[ks*4],     acc0);
            acc1 = MFMA(A1, Bp[(ks+1)*4], acc1);
        }
        float bb = sb1[orow];
        #pragma unroll
        for (int j=0;j<4;++j){
            int r = hr*4 + j;
            hsb[offHs(r, orow)] = (u16)f2bf(eluf(acc0[j] + acc1[j] + bb));
        }
    }
    // (2b) sks partials: wave w covers ks = w*8..w*8+7
    const u16* sWsb = ws + OFF_SWS;
    {
        f32x4 acc = {0,0,0,0};
        const s16x8* Bp = reinterpret_cast<const s16x8*>(sWsb + c16*NVD + hr*8);
        #pragma unroll
        for (int kk = 0; kk < 8; ++kk){
            int ks = w*8 + kk;
            s16x8 Af = *reinterpret_cast<const s16x8*>(&big[offBig(c16, ks*32 + hr*8)]);
            acc = MFMA(Af, Bp[ks*4], acc);
        }
        #pragma unroll
        for (int j=0;j<4;++j)
            pp[w*256 + (hr*4+j)*16 + c16] = acc[j];
    }
    __syncthreads();

    if (t < 256){
        float a = sbs[t & 15];
        #pragma unroll
        for (int ww=0; ww<8; ++ww) a += pp[ww*256 + t];
        sksbuf[t] = a;
    }
    __syncthreads();

    // (4) h2s / gs partials: waves 0-3 -> sW2 (ks=w), waves 4-7 -> sWg
    {
        const u16* Bsrc = (w < 4) ? (ws + OFF_SW2) : (ws + OFF_SWG);
        const int m = w & 3;
        s16x8 Af = *reinterpret_cast<const s16x8*>(&hsb[offHs(c16, m*32 + hr*8)]);
        s16x8 Bf = *reinterpret_cast<const s16x8*>(Bsrc + c16*ND + m*32 + hr*8);
        f32x4 z4 = {0,0,0,0};
        f32x4 acc = MFMA(Af, Bf, z4);
        #pragma unroll
        for (int j=0;j<4;++j)
            pp[w*256 + (hr*4+j)*16 + c16] = acc[j];
    }
    __syncthreads();

    // (5) gate-mix, LN over V, softmax -> weights
    if (t < 256){
        int r = t >> 4, vv = t & 15;
        float h2s = sb2[vv], gp = sbg[vv];
        #pragma unroll
        for (int j=0;j<4;++j){ h2s += pp[j*256 + t]; gp += pp[(4+j)*256 + t]; }
        float gs = sigm(gp);
        float yv = gs*h2s + (1.f-gs)*sksbuf[t];
        float ssum = yv, qsum = yv*yv;
        #pragma unroll
        for (int m=1;m<16;m<<=1){ ssum += __shfl_xor(ssum,m,16); qsum += __shfl_xor(qsum,m,16); }
        float mean = ssum*(1.f/NVAR);
        float var  = qsum*(1.f/NVAR) - mean*mean;
        float z = (yv-mean)*rsqrtf(var+1e-5f)*sgamma[vv] + sbeta[vv];
        float mx = z;
        #pragma unroll
        for (int m=1;m<16;m<<=1) mx = fmaxf(mx, __shfl_xor(mx,m,16));
        float e = expf(z-mx);
        float es = e;
        #pragma unroll
        for (int m=1;m<16;m<<=1) es += __shfl_xor(es,m,16);
        float wgt = e/es;
        wgtbuf[t] = wgt;
        out_w[(row0+r)*NVAR + vv] = wgt;
    }
    __syncthreads();

    // (6) processed = sum_v stacked * weights (vectorized 8-wide)
    if (t < 256){
        int r = t >> 4, d8 = (t & 15)*8;
        float acc[8] = {0,0,0,0,0,0,0,0};
        #pragma unroll
        for (int v=0; v<NVAR; ++v){
            float wv = wgtbuf[r*NVAR + v];
            s16x8 sv = *reinterpret_cast<const s16x8*>(&big[offBig(r, v*ND + d8)]);
            #pragma unroll
            for (int k=0;k<8;++k) acc[k] += bf2f((u16)sv[k]) * wv;
        }
        float* op = &out_proc[(row0+r)*ND + d8];
        #pragma unroll
        for (int k=0;k<8;++k) op[k] = acc[k];
    }
}

extern "C" void kernel_launch(void* const* d_in, const int* in_sizes, int n_in,
                              void* d_out, int out_size, void* d_ws, size_t ws_size,
                              hipStream_t stream) {
    (void)in_sizes; (void)n_in; (void)out_size; (void)ws_size;
    const float* x     = (const float*)d_in[0];
    const float* W1    = (const float*)d_in[1];
    const float* b1    = (const float*)d_in[2];
    const float* W2    = (const float*)d_in[3];
    const float* b2    = (const float*)d_in[4];
    const float* Wg    = (const float*)d_in[5];
    const float* bg    = (const float*)d_in[6];
    const float* Wsk   = (const float*)d_in[7];
    const float* bsk   = (const float*)d_in[8];
    const float* gamma = (const float*)d_in[9];
    const float* beta  = (const float*)d_in[10];
    const float* sW1   = (const float*)d_in[11];
    const float* sb1   = (const float*)d_in[12];
    const float* sW2   = (const float*)d_in[13];
    const float* sb2   = (const float*)d_in[14];
    const float* sWg   = (const float*)d_in[15];
    const float* sbg   = (const float*)d_in[16];
    const float* sWs   = (const float*)d_in[17];
    const float* sbs   = (const float*)d_in[18];
    const float* sgam  = (const float*)d_in[19];
    const float* sbet  = (const float*)d_in[20];

    u16* ws = (u16*)d_ws;
    float* out_proc = (float*)d_out;
    float* out_w    = out_proc + (size_t)NROWS * ND;

    prep_kernel<<<(WS_ELEMS + 255)/256, 256, 0, stream>>>(W2, Wg, sW1, sWs, sW2, sWg, ws);
    vsn_main<<<NBLK, NTH, 0, stream>>>(x, W1, b1, b2, bg, Wsk, bsk, gamma, beta,
                                       sb1, sb2, sbg, sbs, sgam, sbet, ws,
                                       out_proc, out_w);
}